// Round 8
// baseline (295.211 us; speedup 1.0000x reference)
//
#include <hip/hip_runtime.h>
#include <hip/hip_bf16.h>

typedef __bf16 bf16x8 __attribute__((ext_vector_type(8)));
typedef float f32x4 __attribute__((ext_vector_type(4)));

#define D 128           // D_IN == D_OUT == 128
#define EDIM 16
#define CAP 40          // bucket capacity (deg ~ Poisson(8); P(any>40) ~ 1e-10)

__device__ inline unsigned short f2bf(float f) {   // RTNE fp32 -> bf16
    unsigned u = __builtin_bit_cast(unsigned, f);
    u += 0x7fffu + ((u >> 16) & 1u);
    return (unsigned short)(u >> 16);
}

// ---------------------------------------------------------------------------
// K1: FUSED prep. blockIdx % 3 == 0  -> gemm work (1563 blocks),
//     else                           -> bucket-fill work (3125 blocks).
// The latency-bound scatter (fill) hides under the MFMA/streaming gemm.
// ---------------------------------------------------------------------------
__global__ __launch_bounds__(256) void prep_fused(
    const float* __restrict__ x,        // [N,128] fp32
    const float* __restrict__ W,        // [128,128] fp32
    unsigned short* __restrict__ xwb,   // [N,128] bf16
    int ntiles,
    const int* __restrict__ ei,         // [2,E] int32
    int* __restrict__ deg,              // [N]
    int2* __restrict__ perm2,           // [N*CAP] {edge id, src}
    int E)
{
    __shared__ unsigned short Wt[128][136];
    const int t = threadIdx.x;
    const int bid = blockIdx.x;

    if (bid % 3 != 0) {
        // ---------------- bucket fill ----------------
        const int fill_id = bid - bid / 3 - 1;          // 0..3124 monotone
        const int e = fill_id * 256 + t;
        if (e < E) {
            const int src = ei[e];
            const int dst = ei[(size_t)E + e];
            const int pos = atomicAdd(&deg[dst], 1);
            if (pos < CAP) perm2[(size_t)dst * CAP + pos] = make_int2(e, src);
        }
        return;
    }

    // ---------------- gemm: xw = x @ W ----------------
    const int gemm_id = bid / 3;                        // 0..1562
    const int ngemm = (gridDim.x + 2) / 3;

    #pragma unroll
    for (int i = 0; i < 16; ++i) {
        int id = (i * 256 + t) * 4;            // 4 consecutive n at row k
        float4 p = *(const float4*)(W + id);
        int k = id >> 7, n = id & 127;
        Wt[n + 0][k] = f2bf(p.x);
        Wt[n + 1][k] = f2bf(p.y);
        Wt[n + 2][k] = f2bf(p.z);
        Wt[n + 3][k] = f2bf(p.w);
    }
    __syncthreads();

    const int wave = t >> 6, lane = t & 63;
    const int quad = lane >> 4, low = lane & 15;
    const int nwaves = ngemm * 4;

    for (int mt = gemm_id * 4 + wave; mt < ntiles; mt += nwaves) {
        const int arow = mt * 16 + low;
        f32x4 acc[8];
        #pragma unroll
        for (int nt = 0; nt < 8; ++nt) acc[nt] = (f32x4){0.f, 0.f, 0.f, 0.f};

        #pragma unroll
        for (int kc = 0; kc < 4; ++kc) {
            const int k0 = kc * 32 + quad * 8;
            const float* xp = x + (size_t)arow * D + k0;
            float4 a0 = *(const float4*)xp;
            float4 a1 = *(const float4*)(xp + 4);
            union { unsigned short us[8]; bf16x8 v; } a;
            a.us[0] = f2bf(a0.x); a.us[1] = f2bf(a0.y);
            a.us[2] = f2bf(a0.z); a.us[3] = f2bf(a0.w);
            a.us[4] = f2bf(a1.x); a.us[5] = f2bf(a1.y);
            a.us[6] = f2bf(a1.z); a.us[7] = f2bf(a1.w);
            #pragma unroll
            for (int nt = 0; nt < 8; ++nt) {
                bf16x8 bf = *(const bf16x8*)(&Wt[nt * 16 + low][k0]);
                acc[nt] = __builtin_amdgcn_mfma_f32_16x16x32_bf16(a.v, bf, acc[nt], 0, 0, 0);
            }
        }
        #pragma unroll
        for (int nt = 0; nt < 8; ++nt) {
            #pragma unroll
            for (int r = 0; r < 4; ++r) {
                const size_t row = (size_t)mt * 16 + quad * 4 + r;
                xwb[row * D + nt * 16 + low] = f2bf(acc[nt][r]);
            }
        }
    }
}

// ---------------------------------------------------------------------------
// K2: gather. EXACT round-7 body; ONLY change: __launch_bounds__(256,6) ->
// (256,4).  R7 evidence: VGPR_Count=40 < live state (~56: c0/c1=32 + xv[8]
// + slots + addrs) => compiler REMATERIALIZED c0/c1 from ew inside the hot
// loop (lane-dependent addresses -> vector reloads + lgkm waits), roughly
// doubling dynamic VALU work (VALUBusy 50% at 2x the useful inst count).
// A 128-VGPR budget lets c0/c1 stay resident; occupancy was already ~52%
// (~4.2 waves/SIMD), so the 4-wave floor gives up nothing.
// ---------------------------------------------------------------------------
__global__ __launch_bounds__(256, 4) void gather_out(
    const float* __restrict__ ea,          // [E,16] fp32
    const float* __restrict__ ew,          // [16,128] fp32
    const unsigned short* __restrict__ xwb,// [N,128] bf16
    const int* __restrict__ deg,           // [N]
    const int2* __restrict__ perm2,        // [N*CAP] {e, src}
    const float* __restrict__ b,           // [128]
    float* __restrict__ out,               // [N,128] fp32
    int N)
{
    __shared__ float eas[4][128];          // per-wave strip: 8 rows x 16 fp32
    const int t = threadIdx.x, wave = t >> 6, lane = t & 63;
    const int ch = lane * 2;
    float* const my = eas[wave];

    float c0[16], c1[16];
    #pragma unroll
    for (int k = 0; k < 16; ++k) {
        c0[k] = ew[k * D + ch];
        c1[k] = ew[k * D + ch + 1];
    }
    const float b0 = b[ch], b1 = b[ch + 1];

    const int nw = gridDim.x * 4;
    const int lrow = lane >> 3;            // 0..7: row this lane helps load
    const int lcol = (lane & 7) * 2;       // 2 floats per lane

    for (int n = blockIdx.x * 4 + wave; n < N; n += nw) {
        const int nb = __builtin_amdgcn_readfirstlane(n);
        int dg = deg[nb]; dg = dg < CAP ? dg : CAP;        // the only s_load
        const int2* __restrict__ pp = perm2 + (size_t)nb * CAP;
        float a0 = b0, a1 = b1;

        for (int base = 0; base < dg; base += 8) {
            const int rem = dg - base;                     // uniform, >= 1

            // 1. slot vector load (clamped to last valid slot)
            const int ridx = lrow < rem ? lrow : rem - 1;
            const int2 sl = pp[base + ridx];

            // 2. ea row gather: lane fetches its float2 of row sl.x (nt:
            //    single-use stream, keep out of L2)
            const float* ep = ea + (size_t)(unsigned)sl.x * EDIM + lcol;
            float2 v;
            v.x = __builtin_nontemporal_load(ep);
            v.y = __builtin_nontemporal_load(ep + 1);
            *(float2*)(my + lane * 2) = v;                 // [row][16] layout

            // 3. src ids out of the slot reg -> SGPRs (no memory traffic)
            int s[8];
            #pragma unroll
            for (int i = 0; i < 8; ++i)
                s[i] = __builtin_amdgcn_readlane(sl.y, i * 8);

            // 4. xw gathers: SGPR base + lane offset, 1 dword = 2 channels
            unsigned xv[8];
            #pragma unroll
            for (int i = 0; i < 8; ++i)
                xv[i] = *(const unsigned*)(xwb + (size_t)(unsigned)s[i] * D + ch);

            asm volatile("" ::: "memory");   // keep ds_reads after ds_write

            // 5. per-edge: broadcast ds_read of row, 2x16 fmac, fold gather
            #pragma unroll
            for (int i = 0; i < 8; ++i) {
                const float4* r4 = (const float4*)(my + i * 16);
                const float4 r0 = r4[0], r1 = r4[1], r2 = r4[2], r3 = r4[3];
                float m0 = r0.x * c0[0];
                m0 = fmaf(r0.y, c0[1],  m0); m0 = fmaf(r0.z, c0[2],  m0);
                m0 = fmaf(r0.w, c0[3],  m0); m0 = fmaf(r1.x, c0[4],  m0);
                m0 = fmaf(r1.y, c0[5],  m0); m0 = fmaf(r1.z, c0[6],  m0);
                m0 = fmaf(r1.w, c0[7],  m0); m0 = fmaf(r2.x, c0[8],  m0);
                m0 = fmaf(r2.y, c0[9],  m0); m0 = fmaf(r2.z, c0[10], m0);
                m0 = fmaf(r2.w, c0[11], m0); m0 = fmaf(r3.x, c0[12], m0);
                m0 = fmaf(r3.y, c0[13], m0); m0 = fmaf(r3.z, c0[14], m0);
                m0 = fmaf(r3.w, c0[15], m0);
                float m1 = r0.x * c1[0];
                m1 = fmaf(r0.y, c1[1],  m1); m1 = fmaf(r0.z, c1[2],  m1);
                m1 = fmaf(r0.w, c1[3],  m1); m1 = fmaf(r1.x, c1[4],  m1);
                m1 = fmaf(r1.y, c1[5],  m1); m1 = fmaf(r1.z, c1[6],  m1);
                m1 = fmaf(r1.w, c1[7],  m1); m1 = fmaf(r2.x, c1[8],  m1);
                m1 = fmaf(r2.y, c1[9],  m1); m1 = fmaf(r2.z, c1[10], m1);
                m1 = fmaf(r2.w, c1[11], m1); m1 = fmaf(r3.x, c1[12], m1);
                m1 = fmaf(r3.y, c1[13], m1); m1 = fmaf(r3.z, c1[14], m1);
                m1 = fmaf(r3.w, c1[15], m1);
                // inactive slots: force x to +0 (m finite), keep fma unconditional
                const bool act = i < rem;                  // wave-uniform
                const float xlo = act ? __builtin_bit_cast(float, xv[i] << 16) : 0.f;
                const float xhi = act ? __builtin_bit_cast(float, xv[i] & 0xffff0000u) : 0.f;
                a0 = fmaf(m0, xlo, a0);
                a1 = fmaf(m1, xhi, a1);
            }
        }

        // nontemporal: write-once, full lines, no RFO
        float* op = out + (size_t)n * D + ch;
        __builtin_nontemporal_store(a0, op);
        __builtin_nontemporal_store(a1, op + 1);
    }
}

extern "C" void kernel_launch(void* const* d_in, const int* in_sizes, int n_in,
                              void* d_out, int out_size, void* d_ws, size_t ws_size,
                              hipStream_t stream) {
    const float* x  = (const float*)d_in[0];
    const int*   ei = (const int*)d_in[1];
    const float* ea = (const float*)d_in[2];
    const float* W  = (const float*)d_in[3];
    const float* ew = (const float*)d_in[4];
    const float* bb = (const float*)d_in[5];
    float* out = (float*)d_out;

    const int N = in_sizes[0] / D;        // 100000
    const int E = in_sizes[2] / EDIM;     // 800000

    // ws: xwb bf16 25.6MB | deg 0.4MB | perm2 int2 32MB  (~58MB)
    unsigned short* xwb = (unsigned short*)d_ws;
    int* deg   = (int*)(xwb + (size_t)N * D);
    int2* perm2 = (int2*)(deg + N);

    hipMemsetAsync(deg, 0, (size_t)N * sizeof(int), stream);

    const int ntiles = N / 16;                  // 6250 exact
    const int nfill  = (E + 255) / 256;         // 3125
    const int ngemm  = (ntiles + 3) / 4;        // 1563
    prep_fused<<<nfill + ngemm, 256, 0, stream>>>(x, W, xwb, ntiles,
                                                  ei, deg, perm2, E);

    gather_out<<<6144, 256, 0, stream>>>(ea, ew, xwb, deg, perm2, bb, out, N);
}

// Round 10
// 273.905 us; speedup vs baseline: 1.0778x; 1.0778x over previous
//
#include <hip/hip_runtime.h>
#include <hip/hip_bf16.h>

typedef __bf16 bf16x8 __attribute__((ext_vector_type(8)));
typedef float f32x4 __attribute__((ext_vector_type(4)));

#define D 128           // D_IN == D_OUT == 128
#define EDIM 16
#define CAP 40          // bucket capacity (deg ~ Poisson(8); P(any>40) ~ 1e-10)

__device__ inline unsigned short f2bf(float f) {   // RTNE fp32 -> bf16
    unsigned u = __builtin_bit_cast(unsigned, f);
    u += 0x7fffu + ((u >> 16) & 1u);
    return (unsigned short)(u >> 16);
}

// ---------------------------------------------------------------------------
// K1: FUSED prep. blockIdx % 3 == 0  -> gemm work (1563 blocks),
//     else                           -> bucket-fill work (3125 blocks).
// The latency-bound scatter (fill) hides under the MFMA/streaming gemm.
// (Verified: "rest" 187 -> ~175 us.)  NO cooperative launch (R9: core dump).
// ---------------------------------------------------------------------------
__global__ __launch_bounds__(256) void prep_fused(
    const float* __restrict__ x,        // [N,128] fp32
    const float* __restrict__ W,        // [128,128] fp32
    unsigned short* __restrict__ xwb,   // [N,128] bf16
    int ntiles,
    const int* __restrict__ ei,         // [2,E] int32
    int* __restrict__ deg,              // [N]
    int2* __restrict__ perm2,           // [N*CAP] {edge id, src}
    int E)
{
    __shared__ unsigned short Wt[128][136];
    const int t = threadIdx.x;
    const int bid = blockIdx.x;

    if (bid % 3 != 0) {
        // ---------------- bucket fill ----------------
        const int fill_id = bid - bid / 3 - 1;          // 0..3124 monotone
        const int e = fill_id * 256 + t;
        if (e < E) {
            const int src = ei[e];
            const int dst = ei[(size_t)E + e];
            const int pos = atomicAdd(&deg[dst], 1);
            if (pos < CAP) perm2[(size_t)dst * CAP + pos] = make_int2(e, src);
        }
        return;
    }

    // ---------------- gemm: xw = x @ W ----------------
    const int gemm_id = bid / 3;                        // 0..1562
    const int ngemm = (gridDim.x + 2) / 3;

    #pragma unroll
    for (int i = 0; i < 16; ++i) {
        int id = (i * 256 + t) * 4;            // 4 consecutive n at row k
        float4 p = *(const float4*)(W + id);
        int k = id >> 7, n = id & 127;
        Wt[n + 0][k] = f2bf(p.x);
        Wt[n + 1][k] = f2bf(p.y);
        Wt[n + 2][k] = f2bf(p.z);
        Wt[n + 3][k] = f2bf(p.w);
    }
    __syncthreads();

    const int wave = t >> 6, lane = t & 63;
    const int quad = lane >> 4, low = lane & 15;
    const int nwaves = ngemm * 4;

    for (int mt = gemm_id * 4 + wave; mt < ntiles; mt += nwaves) {
        const int arow = mt * 16 + low;
        f32x4 acc[8];
        #pragma unroll
        for (int nt = 0; nt < 8; ++nt) acc[nt] = (f32x4){0.f, 0.f, 0.f, 0.f};

        #pragma unroll
        for (int kc = 0; kc < 4; ++kc) {
            const int k0 = kc * 32 + quad * 8;
            const float* xp = x + (size_t)arow * D + k0;
            float4 a0 = *(const float4*)xp;
            float4 a1 = *(const float4*)(xp + 4);
            union { unsigned short us[8]; bf16x8 v; } a;
            a.us[0] = f2bf(a0.x); a.us[1] = f2bf(a0.y);
            a.us[2] = f2bf(a0.z); a.us[3] = f2bf(a0.w);
            a.us[4] = f2bf(a1.x); a.us[5] = f2bf(a1.y);
            a.us[6] = f2bf(a1.z); a.us[7] = f2bf(a1.w);
            #pragma unroll
            for (int nt = 0; nt < 8; ++nt) {
                bf16x8 bf = *(const bf16x8*)(&Wt[nt * 16 + low][k0]);
                acc[nt] = __builtin_amdgcn_mfma_f32_16x16x32_bf16(a.v, bf, acc[nt], 0, 0, 0);
            }
        }
        #pragma unroll
        for (int nt = 0; nt < 8; ++nt) {
            #pragma unroll
            for (int r = 0; r < 4; ++r) {
                const size_t row = (size_t)mt * 16 + quad * 4 + r;
                xwb[row * D + nt * 16 + low] = f2bf(acc[nt][r]);
            }
        }
    }
}

// ---------------------------------------------------------------------------
// K2: gather. EXACT round-7 body (best: 112us, WRITE 50MB clean); ONLY
// change: __launch_bounds__(256,6) -> (256,8).
// Evidence (R7 vs R8): VALU TIME is identical at alloc 40 vs 52 (remat is
// costless); dur tracks OCCUPANCY (52% -> 112us, 35% -> 119us). Body fits
// in 40-52 VGPR < the 64-cap at 8 waves/EU (R5's spill needed >64), so
// raising the wave ceiling 6->8/SIMD buys latency hiding for free.
// Tripwire: WRITE_SIZE >> 50MB = spill => revert to (256,6).
// ---------------------------------------------------------------------------
__global__ __launch_bounds__(256, 8) void gather_out(
    const float* __restrict__ ea,          // [E,16] fp32
    const float* __restrict__ ew,          // [16,128] fp32
    const unsigned short* __restrict__ xwb,// [N,128] bf16
    const int* __restrict__ deg,           // [N]
    const int2* __restrict__ perm2,        // [N*CAP] {e, src}
    const float* __restrict__ b,           // [128]
    float* __restrict__ out,               // [N,128] fp32
    int N)
{
    __shared__ float eas[4][128];          // per-wave strip: 8 rows x 16 fp32
    const int t = threadIdx.x, wave = t >> 6, lane = t & 63;
    const int ch = lane * 2;
    float* const my = eas[wave];

    float c0[16], c1[16];
    #pragma unroll
    for (int k = 0; k < 16; ++k) {
        c0[k] = ew[k * D + ch];
        c1[k] = ew[k * D + ch + 1];
    }
    const float b0 = b[ch], b1 = b[ch + 1];

    const int nw = gridDim.x * 4;
    const int lrow = lane >> 3;            // 0..7: row this lane helps load
    const int lcol = (lane & 7) * 2;       // 2 floats per lane

    for (int n = blockIdx.x * 4 + wave; n < N; n += nw) {
        const int nb = __builtin_amdgcn_readfirstlane(n);
        int dg = deg[nb]; dg = dg < CAP ? dg : CAP;        // the only s_load
        const int2* __restrict__ pp = perm2 + (size_t)nb * CAP;
        float a0 = b0, a1 = b1;

        for (int base = 0; base < dg; base += 8) {
            const int rem = dg - base;                     // uniform, >= 1

            // 1. slot vector load (clamped to last valid slot)
            const int ridx = lrow < rem ? lrow : rem - 1;
            const int2 sl = pp[base + ridx];

            // 2. ea row gather: lane fetches its float2 of row sl.x (nt:
            //    single-use stream, keep out of L2)
            const float* ep = ea + (size_t)(unsigned)sl.x * EDIM + lcol;
            float2 v;
            v.x = __builtin_nontemporal_load(ep);
            v.y = __builtin_nontemporal_load(ep + 1);
            *(float2*)(my + lane * 2) = v;                 // [row][16] layout

            // 3. src ids out of the slot reg -> SGPRs (no memory traffic)
            int s[8];
            #pragma unroll
            for (int i = 0; i < 8; ++i)
                s[i] = __builtin_amdgcn_readlane(sl.y, i * 8);

            // 4. xw gathers: SGPR base + lane offset, 1 dword = 2 channels
            unsigned xv[8];
            #pragma unroll
            for (int i = 0; i < 8; ++i)
                xv[i] = *(const unsigned*)(xwb + (size_t)(unsigned)s[i] * D + ch);

            asm volatile("" ::: "memory");   // keep ds_reads after ds_write

            // 5. per-edge: broadcast ds_read of row, 2x16 fmac, fold gather
            #pragma unroll
            for (int i = 0; i < 8; ++i) {
                const float4* r4 = (const float4*)(my + i * 16);
                const float4 r0 = r4[0], r1 = r4[1], r2 = r4[2], r3 = r4[3];
                float m0 = r0.x * c0[0];
                m0 = fmaf(r0.y, c0[1],  m0); m0 = fmaf(r0.z, c0[2],  m0);
                m0 = fmaf(r0.w, c0[3],  m0); m0 = fmaf(r1.x, c0[4],  m0);
                m0 = fmaf(r1.y, c0[5],  m0); m0 = fmaf(r1.z, c0[6],  m0);
                m0 = fmaf(r1.w, c0[7],  m0); m0 = fmaf(r2.x, c0[8],  m0);
                m0 = fmaf(r2.y, c0[9],  m0); m0 = fmaf(r2.z, c0[10], m0);
                m0 = fmaf(r2.w, c0[11], m0); m0 = fmaf(r3.x, c0[12], m0);
                m0 = fmaf(r3.y, c0[13], m0); m0 = fmaf(r3.z, c0[14], m0);
                m0 = fmaf(r3.w, c0[15], m0);
                float m1 = r0.x * c1[0];
                m1 = fmaf(r0.y, c1[1],  m1); m1 = fmaf(r0.z, c1[2],  m1);
                m1 = fmaf(r0.w, c1[3],  m1); m1 = fmaf(r1.x, c1[4],  m1);
                m1 = fmaf(r1.y, c1[5],  m1); m1 = fmaf(r1.z, c1[6],  m1);
                m1 = fmaf(r1.w, c1[7],  m1); m1 = fmaf(r2.x, c1[8],  m1);
                m1 = fmaf(r2.y, c1[9],  m1); m1 = fmaf(r2.z, c1[10], m1);
                m1 = fmaf(r2.w, c1[11], m1); m1 = fmaf(r3.x, c1[12], m1);
                m1 = fmaf(r3.y, c1[13], m1); m1 = fmaf(r3.z, c1[14], m1);
                m1 = fmaf(r3.w, c1[15], m1);
                // inactive slots: force x to +0 (m finite), keep fma unconditional
                const bool act = i < rem;                  // wave-uniform
                const float xlo = act ? __builtin_bit_cast(float, xv[i] << 16) : 0.f;
                const float xhi = act ? __builtin_bit_cast(float, xv[i] & 0xffff0000u) : 0.f;
                a0 = fmaf(m0, xlo, a0);
                a1 = fmaf(m1, xhi, a1);
            }
        }

        // nontemporal: write-once, full lines, no RFO
        float* op = out + (size_t)n * D + ch;
        __builtin_nontemporal_store(a0, op);
        __builtin_nontemporal_store(a1, op + 1);
    }
}

extern "C" void kernel_launch(void* const* d_in, const int* in_sizes, int n_in,
                              void* d_out, int out_size, void* d_ws, size_t ws_size,
                              hipStream_t stream) {
    const float* x  = (const float*)d_in[0];
    const int*   ei = (const int*)d_in[1];
    const float* ea = (const float*)d_in[2];
    const float* W  = (const float*)d_in[3];
    const float* ew = (const float*)d_in[4];
    const float* bb = (const float*)d_in[5];
    float* out = (float*)d_out;

    const int N = in_sizes[0] / D;        // 100000
    const int E = in_sizes[2] / EDIM;     // 800000

    // ws: xwb bf16 25.6MB | deg 0.4MB | perm2 int2 32MB  (~58MB)
    unsigned short* xwb = (unsigned short*)d_ws;
    int* deg   = (int*)(xwb + (size_t)N * D);
    int2* perm2 = (int2*)(deg + N);

    hipMemsetAsync(deg, 0, (size_t)N * sizeof(int), stream);

    const int ntiles = N / 16;                  // 6250 exact
    const int nfill  = (E + 255) / 256;         // 3125
    const int ngemm  = (ntiles + 3) / 4;        // 1563
    prep_fused<<<nfill + ngemm, 256, 0, stream>>>(x, W, xwb, ntiles,
                                                  ei, deg, perm2, E);

    gather_out<<<6144, 256, 0, stream>>>(ea, ew, xwb, deg, perm2, bb, out, N);
}